// Round 1
// 66.512 us; speedup vs baseline: 1.0231x; 1.0231x over previous
//
#include <hip/hip_runtime.h>

// QGenModel self_diff_attention, algebraically factored (exact, fp32):
//   logits[b,n,g] = sum_d obj[b,n,d]^2 * S[g,d] - obj[b,n,d] * T[b,g,d] + bias[g]
//     S[g,d]   = sum_m W[g,m,d]
//     T[b,g,d] = sum_m W[g,m,d] * obj[b,m,d]
// masked softmax over n, then vis[b,g,d] = sum_n w[b,n,g]*obj[b,n,d].
//
// Round-4 change: single global-memory phase.
//  - thread (q = t>>7, r = t&127) owns float4 d-chunk [4r,4r+4) and the
//    m-subset {q, q+4, ..., q+32}: 18 float4 loads/thread (was 108 scalar
//    loads across two latency phases).
//  - logits computed from registers (o[] kept live) + LDS-reduced S/T;
//    the old pass-2 re-read of obj (73.7 KB L2 per block) is gone.
//  - mask/bias prefetched at entry so softmax phase has no load latency.

#define QB 128
#define QN 36
#define QD 512
#define QG 2
#define NMQ 9    // m's per q-group (36/4)
#define NR 128   // float4 chunks per row (512/4)

__global__ __launch_bounds__(512) void qgen_self_diff_attn(
    const float* __restrict__ obj,   // [B, N, D]
    const float* __restrict__ W,     // [G, N*D]
    const float* __restrict__ bias,  // [G]
    const int* __restrict__ mask,    // [B, N] (0/1)
    float* __restrict__ out)         // [B, G*D]
{
    __shared__ float4 s_T[4][NR];    // 8 KiB (reused for vis partials)
    __shared__ float4 s_S[4][NR];    // 8 KiB
    __shared__ float  s_lp[8][NMQ];  // per-wave logit partials
    __shared__ float  s_w[QN];

    const int bid  = blockIdx.x;
    const int b    = bid & (QB - 1);   // batch
    const int g    = bid >> 7;         // glimpse; pairs share an XCD (128%8==0)
    const int t    = threadIdx.x;
    const int q    = t >> 7;           // 0..3  : m-subset
    const int r    = t & (NR - 1);     // 0..127: d-chunk index
    const int wave = t >> 6;
    const int lane = t & 63;

    // Prefetch softmax-phase operands; latency hides under pass 1.
    int   mk = 1;
    float bg = 0.f;
    if (wave == 0) {
        bg = bias[g];
        if (lane < QN) mk = mask[b * QN + lane];
    }

    const float4* ob4 = (const float4*)(obj + (size_t)b * QN * QD);
    const float4* wg4 = (const float4*)(W   + (size_t)g * QN * QD);

    // ---- Pass 1 (only global phase): load o-chunks, accumulate partial T,S
    float4 o[NMQ];
    float4 Tp = make_float4(0.f, 0.f, 0.f, 0.f);
    float4 Sp = make_float4(0.f, 0.f, 0.f, 0.f);
    #pragma unroll
    for (int j = 0; j < NMQ; ++j) {
        const int m = q + 4 * j;
        const float4 ov = ob4[m * NR + r];   // 64 lanes x 16B contiguous
        const float4 wv = wg4[m * NR + r];
        o[j] = ov;
        Tp.x = fmaf(wv.x, ov.x, Tp.x); Tp.y = fmaf(wv.y, ov.y, Tp.y);
        Tp.z = fmaf(wv.z, ov.z, Tp.z); Tp.w = fmaf(wv.w, ov.w, Tp.w);
        Sp.x += wv.x; Sp.y += wv.y; Sp.z += wv.z; Sp.w += wv.w;
    }
    s_T[q][r] = Tp;
    s_S[q][r] = Sp;
    __syncthreads();

    // ---- Full T,S for this thread's d-chunk (sum the 4 q-partials)
    float4 T = s_T[0][r], S = s_S[0][r];
    #pragma unroll
    for (int k = 1; k < 4; ++k) {
        const float4 a = s_T[k][r], c = s_S[k][r];
        T.x += a.x; T.y += a.y; T.z += a.z; T.w += a.w;
        S.x += c.x; S.y += c.y; S.z += c.z; S.w += c.w;
    }

    // ---- Logit partials from registers: p[n] = sum_d o*(o*S - T)
    float p[NMQ];
    #pragma unroll
    for (int j = 0; j < NMQ; ++j) {
        const float4 ov = o[j];
        float a;
        a  = ov.x * fmaf(ov.x, S.x, -T.x);
        a += ov.y * fmaf(ov.y, S.y, -T.y);
        a += ov.z * fmaf(ov.z, S.z, -T.z);
        a += ov.w * fmaf(ov.w, S.w, -T.w);
        p[j] = a;
    }
    // Wave-reduce each of the 9 partials; threads with m-subset q live in
    // waves 2q and 2q+1, combined via s_lp below.
    #pragma unroll
    for (int j = 0; j < NMQ; ++j) {
        float a = p[j];
        #pragma unroll
        for (int off = 32; off; off >>= 1)
            a += __shfl_down(a, off);
        if (lane == 0) s_lp[wave][j] = a;
    }
    __syncthreads();

    // ---- Masked softmax over n (wave 0, all lanes active)
    if (wave == 0) {
        float l = -3e38f;
        if (lane < QN) {
            const int nq = lane & 3, nj = lane >> 2;
            const float v = s_lp[2 * nq][nj] + s_lp[2 * nq + 1][nj];
            l = mk ? v + bg : -1e10f;
        }
        float mx = l;
        #pragma unroll
        for (int off = 32; off; off >>= 1)
            mx = fmaxf(mx, __shfl_xor(mx, off));
        const float e = (lane < QN) ? __expf(l - mx) : 0.f;
        float sm = e;
        #pragma unroll
        for (int off = 32; off; off >>= 1)
            sm += __shfl_xor(sm, off);
        if (lane < QN) s_w[lane] = e / sm;
    }
    __syncthreads();

    // ---- vis partial over this thread's 9 m's (from registers), then
    //      cross-q sum via LDS (s_T reused; its reads all pre-date barrier 2)
    float4 acc = make_float4(0.f, 0.f, 0.f, 0.f);
    #pragma unroll
    for (int j = 0; j < NMQ; ++j) {
        const float wn = s_w[q + 4 * j];
        const float4 ov = o[j];
        acc.x = fmaf(wn, ov.x, acc.x); acc.y = fmaf(wn, ov.y, acc.y);
        acc.z = fmaf(wn, ov.z, acc.z); acc.w = fmaf(wn, ov.w, acc.w);
    }
    s_T[q][r] = acc;
    __syncthreads();

    const float* sv = (const float*)&s_T[0][0];   // flat [4][512]
    const float v = sv[t] + sv[512 + t] + sv[1024 + t] + sv[1536 + t];
    out[(size_t)b * (QG * QD) + (size_t)g * QD + t] = v;
}

extern "C" void kernel_launch(void* const* d_in, const int* in_sizes, int n_in,
                              void* d_out, int out_size, void* d_ws, size_t ws_size,
                              hipStream_t stream) {
    const float* obj  = (const float*)d_in[0];
    const float* W    = (const float*)d_in[1];
    const float* bias = (const float*)d_in[2];
    const int*   mask = (const int*)d_in[3];
    float* out = (float*)d_out;

    qgen_self_diff_attn<<<QB * QG, 512, 0, stream>>>(obj, W, bias, mask, out);
}

// Round 2
// 66.268 us; speedup vs baseline: 1.0268x; 1.0037x over previous
//
#include <hip/hip_runtime.h>

// QGenModel self_diff_attention, algebraically factored (exact, fp32):
//   logits[b,n,g] = sum_d obj[b,n,d]^2 * S[g,d] - obj[b,n,d] * T[b,g,d] + bias[g]
//     S[g,d]   = sum_m W[g,m,d]
//     T[b,g,d] = sum_m W[g,m,d] * obj[b,m,d]
// masked softmax over n, then vis[b,g,d] = sum_n w[b,n,g]*obj[b,n,d].
//
// Round-5 change: occupancy. 1024 threads/block (4 waves/SIMD, was 2) so
// pass-1 HBM latency and barrier phases overlap across twice as many waves.
// Thread (q = t>>7 in 0..7, r = t&127) owns float4 d-chunk [4r,4r+4) and
// m-subset {q, q+8, ...} (5 m's for q<4, 4 for q>=4): 10 float4 loads/thread.

#define QB 128
#define QN 36
#define QD 512
#define QG 2
#define NQ 8     // q-groups
#define NMQ 5    // max m's per q-group (ceil(36/8))
#define NR 128   // float4 chunks per row (512/4)

__global__ __launch_bounds__(1024) void qgen_self_diff_attn(
    const float* __restrict__ obj,   // [B, N, D]
    const float* __restrict__ W,     // [G, N*D]
    const float* __restrict__ bias,  // [G]
    const int* __restrict__ mask,    // [B, N] (0/1)
    float* __restrict__ out)         // [B, G*D]
{
    __shared__ float4 s_T[NQ][NR];   // 16 KiB (reused for vis partials)
    __shared__ float4 s_S[NQ][NR];   // 16 KiB
    __shared__ float  s_lp[16][NMQ]; // per-wave logit partials
    __shared__ float  s_w[QN];

    const int bid  = blockIdx.x;
    const int b    = bid & (QB - 1);   // batch
    const int g    = bid >> 7;         // glimpse; pairs share an XCD (128%8==0)
    const int t    = threadIdx.x;
    const int q    = t >> 7;           // 0..7  : m-subset
    const int r    = t & (NR - 1);     // 0..127: d-chunk index
    const int wave = t >> 6;           // 0..15
    const int lane = t & 63;

    // Prefetch softmax-phase operands; latency hides under pass 1.
    int   mk = 1;
    float bg = 0.f;
    if (wave == 0) {
        bg = bias[g];
        if (lane < QN) mk = mask[b * QN + lane];
    }

    const float4* ob4 = (const float4*)(obj + (size_t)b * QN * QD);
    const float4* wg4 = (const float4*)(W   + (size_t)g * QN * QD);

    // ---- Pass 1 (only global phase): load o-chunks, accumulate partial T,S
    float4 o[NMQ];
    float4 Tp = make_float4(0.f, 0.f, 0.f, 0.f);
    float4 Sp = make_float4(0.f, 0.f, 0.f, 0.f);
    #pragma unroll
    for (int j = 0; j < NMQ; ++j) {
        const int m = q + NQ * j;
        o[j] = make_float4(0.f, 0.f, 0.f, 0.f);
        if (m < QN) {                         // uniform per q-group (2 waves)
            const float4 ov = ob4[m * NR + r];
            const float4 wv = wg4[m * NR + r];
            o[j] = ov;
            Tp.x = fmaf(wv.x, ov.x, Tp.x); Tp.y = fmaf(wv.y, ov.y, Tp.y);
            Tp.z = fmaf(wv.z, ov.z, Tp.z); Tp.w = fmaf(wv.w, ov.w, Tp.w);
            Sp.x += wv.x; Sp.y += wv.y; Sp.z += wv.z; Sp.w += wv.w;
        }
    }
    s_T[q][r] = Tp;
    s_S[q][r] = Sp;
    __syncthreads();

    // ---- Full T,S for this thread's d-chunk (sum the 8 q-partials)
    float4 T = s_T[0][r], S = s_S[0][r];
    #pragma unroll
    for (int k = 1; k < NQ; ++k) {
        const float4 a = s_T[k][r], c = s_S[k][r];
        T.x += a.x; T.y += a.y; T.z += a.z; T.w += a.w;
        S.x += c.x; S.y += c.y; S.z += c.z; S.w += c.w;
    }

    // ---- Logit partials from registers: p[n] = sum_d o*(o*S - T)
    //      wave-reduce each; waves 2q, 2q+1 hold the two d-halves of group q
    #pragma unroll
    for (int j = 0; j < NMQ; ++j) {
        const float4 ov = o[j];
        float a;
        a  = ov.x * fmaf(ov.x, S.x, -T.x);
        a += ov.y * fmaf(ov.y, S.y, -T.y);
        a += ov.z * fmaf(ov.z, S.z, -T.z);
        a += ov.w * fmaf(ov.w, S.w, -T.w);
        #pragma unroll
        for (int off = 32; off; off >>= 1)
            a += __shfl_down(a, off);
        if (lane == 0) s_lp[wave][j] = a;
    }
    __syncthreads();

    // ---- Masked softmax over n (wave 0, all lanes active)
    if (wave == 0) {
        float l = -3e38f;
        if (lane < QN) {
            const int nq = lane & 7, nj = lane >> 3;   // n = nq + 8*nj
            const float v = s_lp[2 * nq][nj] + s_lp[2 * nq + 1][nj];
            l = mk ? v + bg : -1e10f;
        }
        float mx = l;
        #pragma unroll
        for (int off = 32; off; off >>= 1)
            mx = fmaxf(mx, __shfl_xor(mx, off));
        const float e = (lane < QN) ? __expf(l - mx) : 0.f;
        float sm = e;
        #pragma unroll
        for (int off = 32; off; off >>= 1)
            sm += __shfl_xor(sm, off);
        if (lane < QN) s_w[lane] = e / sm;
    }
    __syncthreads();

    // ---- vis partial over this thread's m's (from registers), then
    //      cross-q sum via LDS (s_T reused; its reads all pre-date barrier 2)
    float4 acc = make_float4(0.f, 0.f, 0.f, 0.f);
    #pragma unroll
    for (int j = 0; j < NMQ; ++j) {
        const int m = q + NQ * j;
        if (m < QN) {
            const float wn = s_w[m];
            const float4 ov = o[j];
            acc.x = fmaf(wn, ov.x, acc.x); acc.y = fmaf(wn, ov.y, acc.y);
            acc.z = fmaf(wn, ov.z, acc.z); acc.w = fmaf(wn, ov.w, acc.w);
        }
    }
    s_T[q][r] = acc;
    __syncthreads();

    if (t < QD) {
        const float* sv = (const float*)&s_T[0][0];   // flat [8][512]
        float v = 0.f;
        #pragma unroll
        for (int k = 0; k < NQ; ++k) v += sv[k * QD + t];
        out[(size_t)b * (QG * QD) + (size_t)g * QD + t] = v;
    }
}

extern "C" void kernel_launch(void* const* d_in, const int* in_sizes, int n_in,
                              void* d_out, int out_size, void* d_ws, size_t ws_size,
                              hipStream_t stream) {
    const float* obj  = (const float*)d_in[0];
    const float* W    = (const float*)d_in[1];
    const float* bias = (const float*)d_in[2];
    const int*   mask = (const int*)d_in[3];
    float* out = (float*)d_out;

    qgen_self_diff_attn<<<QB * QG, 1024, 0, stream>>>(obj, W, bias, mask, out);
}